// Round 23
// baseline (155.423 us; speedup 1.0000x reference)
//
#include <hip/hip_runtime.h>
#include <hip/hip_bf16.h>
#include <math.h>

typedef __attribute__((ext_vector_type(8))) short bf16x8;
typedef __attribute__((ext_vector_type(4))) float f32x4;
typedef __attribute__((ext_vector_type(4))) unsigned int u32x4;
typedef __attribute__((ext_vector_type(2))) unsigned int u32x2;

constexpr int NB = 16, NQ = 4096, LF = 2048, C = 256;

__device__ __forceinline__ unsigned short bfbits(float x) {
    return __builtin_bit_cast(unsigned short, __float2bfloat16(x));
}
__device__ __forceinline__ unsigned pk2(float a, float b) {
    return (unsigned)bfbits(a) | ((unsigned)bfbits(b) << 16);
}
__device__ __forceinline__ float bflo(unsigned d) { return __builtin_bit_cast(float, d << 16); }
__device__ __forceinline__ float bfhi(unsigned d) { return __builtin_bit_cast(float, d & 0xffff0000u); }

// ---- prep: weights -> bf16 fragment-linear layout in ws (R4-verified) ----
__global__ void prep_weights(const float* __restrict__ c1w1, const float* __restrict__ c2w1,
                             const float* __restrict__ c1w2, const float* __restrict__ c2w2,
                             const float* __restrict__ gw1, unsigned short* __restrict__ ws)
{
    int t = blockIdx.x * 256 + threadIdx.x;          // 0..24575
    const float* src; int K, nks, dstoff, f;
    if (t < 2048)      { src = c1w1; K = 256; nks = 8;  dstoff = 0;      f = t; }
    else if (t < 4096) { src = c2w1; K = 256; nks = 8;  dstoff = 16384;  f = t - 2048; }
    else if (t < 6144) { src = c1w2; K = 64;  nks = 2;  dstoff = 32768;  f = t - 4096; }
    else if (t < 8192) { src = c2w2; K = 64;  nks = 2;  dstoff = 49152;  f = t - 6144; }
    else               { src = gw1;  K = 512; nks = 16; dstoff = 65536;  f = t - 8192; }
    int l = f & 63, s = f >> 6;
    int nt = s / nks, ks = s % nks;
    int n  = nt * 16 + (l & 15);
    int k0 = ks * 32 + (l >> 4) * 8;
    unsigned short* d = ws + dstoff + (size_t)f * 8;
    const float* sp = src + (size_t)n * K + k0;
    #pragma unroll
    for (int e = 0; e < 8; ++e) d[e] = bfbits(sp[e]);
}

// ---- main: v22 + partial unroll(2) on GEMM1/passA/gate loops (load ILP x2) ----
__global__ __launch_bounds__(256, 4)
void semalign_v23(const float* __restrict__ feat,  const float* __restrict__ qbox,
                  const float* __restrict__ qfeat, const float* __restrict__ posf,
                  const float* __restrict__ c1b1,  const float* __restrict__ c1b2,
                  const float* __restrict__ c1g,   const float* __restrict__ c1be,
                  const float* __restrict__ c2b1,  const float* __restrict__ c2b2,
                  const float* __restrict__ c2g,   const float* __restrict__ c2be,
                  const float* __restrict__ gb1,   const float* __restrict__ gw2,
                  const float* __restrict__ gb2,
                  const unsigned short* __restrict__ wsb,
                  float* __restrict__ out)
{
    // per-wave 8 KiB region: H0 at +0 (2K), H1 at +2048 (2K) during GEMM1;
    // pooled [16][256] bf16 overwrites the whole region in pass B (H already in regs).
    __shared__ __align__(16) unsigned short sP[4][16][256];

    const int tid = threadIdx.x, l = tid & 63, wid = tid >> 6;
    const int lr = l & 15, lg = l >> 4;
    const int rowb = blockIdx.x * 64 + wid * 16;
    const int q = rowb >> 4;
    const int b = lr;
    const int swz = (lr & 7) << 4;

    const float* prow = posf  + ((size_t)b * NQ + q) * C;
    const float* qrow = qfeat + ((size_t)b * NQ + q) * C;
    float cx = qbox[((size_t)b * NQ + q) * 2 + 0];
    float w  = qbox[((size_t)b * NQ + q) * 2 + 1];
    float fs = fminf(fmaxf((cx - 0.5f * w) * (float)LF, 0.f), (float)(LF - 1));
    float fe = fminf(fmaxf((cx + 0.5f * w) * (float)LF, 0.f), (float)(LF - 1));
    const float* srow = feat + ((size_t)b * LF + (int)rintf(fs)) * C;
    const float* erow = feat + ((size_t)b * LF + (int)rintf(fe)) * C;

    // ---------- GEMM1: inline frags, unroll 2 (load ILP without full-unroll spill) ----------
    char* pb = (char*)&sP[wid][0][0];
    {
        f32x4 a1[4] = {}, a2[4] = {};
        #pragma unroll 2
        for (int ks = 0; ks < 8; ++ks) {
            int k0 = ks * 32 + lg * 8;
            float4 s0 = *(const float4*)(srow + k0), s1 = *(const float4*)(srow + k0 + 4);
            float4 e0 = *(const float4*)(erow + k0), e1 = *(const float4*)(erow + k0 + 4);
            float4 p0 = *(const float4*)(prow + k0), p1 = *(const float4*)(prow + k0 + 4);
            u32x4 av, cv;
            av[0] = pk2(s0.x * p0.x, s0.y * p0.y); av[1] = pk2(s0.z * p0.z, s0.w * p0.w);
            av[2] = pk2(s1.x * p1.x, s1.y * p1.y); av[3] = pk2(s1.z * p1.z, s1.w * p1.w);
            cv[0] = pk2(e0.x * p0.x, e0.y * p0.y); cv[1] = pk2(e0.z * p0.z, e0.w * p0.w);
            cv[2] = pk2(e1.x * p1.x, e1.y * p1.y); cv[3] = pk2(e1.z * p1.z, e1.w * p1.w);
            bf16x8 v1 = __builtin_bit_cast(bf16x8, av);
            bf16x8 v2 = __builtin_bit_cast(bf16x8, cv);
            #pragma unroll
            for (int nt = 0; nt < 4; ++nt) {
                bf16x8 wA = *(const bf16x8*)(wsb + ((size_t)((nt * 8 + ks) * 64 + l)) * 8);
                bf16x8 wB = *(const bf16x8*)(wsb + 16384 + ((size_t)((nt * 8 + ks) * 64 + l)) * 8);
                a1[nt] = __builtin_amdgcn_mfma_f32_16x16x32_bf16(wA, v1, a1[nt], 0, 0, 0);
                a2[nt] = __builtin_amdgcn_mfma_f32_16x16x32_bf16(wB, v2, a2[nt], 0, 0, 0);
            }
        }
        #pragma unroll
        for (int nt = 0; nt < 4; ++nt) {
            float4 b1v = *(const float4*)(c1b1 + nt * 16 + lg * 4);
            float4 b2v = *(const float4*)(c2b1 + nt * 16 + lg * 4);
            u32x2 wv;
            wv[0] = pk2(fmaxf(a1[nt][0] + b1v.x, 0.f), fmaxf(a1[nt][1] + b1v.y, 0.f));
            wv[1] = pk2(fmaxf(a1[nt][2] + b1v.z, 0.f), fmaxf(a1[nt][3] + b1v.w, 0.f));
            *(u32x2*)(pb + lr * 128 + ((nt * 32 + lg * 8) ^ swz)) = wv;
            wv[0] = pk2(fmaxf(a2[nt][0] + b2v.x, 0.f), fmaxf(a2[nt][1] + b2v.y, 0.f));
            wv[1] = pk2(fmaxf(a2[nt][2] + b2v.z, 0.f), fmaxf(a2[nt][3] + b2v.w, 0.f));
            *(u32x2*)(pb + 2048 + lr * 128 + ((nt * 32 + lg * 8) ^ swz)) = wv;
        }
    }

    // H frags for BOTH contrasts -> 16 VGPRs; LDS H region then dead
    asm volatile("s_waitcnt lgkmcnt(0)" ::: "memory");
    bf16x8 hfA0 = *(const bf16x8*)(pb + lr * 128 + ((0  + lg * 16) ^ swz));
    bf16x8 hfA1 = *(const bf16x8*)(pb + lr * 128 + ((64 + lg * 16) ^ swz));
    bf16x8 hfB0 = *(const bf16x8*)(pb + 2048 + lr * 128 + ((0  + lg * 16) ^ swz));
    bf16x8 hfB1 = *(const bf16x8*)(pb + 2048 + lr * 128 + ((64 + lg * 16) ^ swz));
    asm volatile("s_waitcnt lgkmcnt(0)" ::: "memory");

    // ---------- GEMM2 pass A: stats only, unroll 2 ----------
    float S1 = 0.f, Q21 = 0.f, S2 = 0.f, Q22 = 0.f;
    #pragma unroll 2
    for (int nt = 0; nt < 16; ++nt) {
        {
            f32x4 u = {};
            bf16x8 wA = *(const bf16x8*)(wsb + 32768 + ((size_t)((nt * 2 + 0) * 64 + l)) * 8);
            bf16x8 wB = *(const bf16x8*)(wsb + 32768 + ((size_t)((nt * 2 + 1) * 64 + l)) * 8);
            u = __builtin_amdgcn_mfma_f32_16x16x32_bf16(wA, hfA0, u, 0, 0, 0);
            u = __builtin_amdgcn_mfma_f32_16x16x32_bf16(wB, hfA1, u, 0, 0, 0);
            float4 bv = *(const float4*)(c1b2 + nt * 16 + lg * 4);
            float v0 = u[0] + bv.x, v1 = u[1] + bv.y, v2 = u[2] + bv.z, v3 = u[3] + bv.w;
            S1 += v0 + v1 + v2 + v3;
            Q21 += v0 * v0 + v1 * v1 + v2 * v2 + v3 * v3;
        }
        {
            f32x4 u = {};
            bf16x8 wA = *(const bf16x8*)(wsb + 49152 + ((size_t)((nt * 2 + 0) * 64 + l)) * 8);
            bf16x8 wB = *(const bf16x8*)(wsb + 49152 + ((size_t)((nt * 2 + 1) * 64 + l)) * 8);
            u = __builtin_amdgcn_mfma_f32_16x16x32_bf16(wA, hfB0, u, 0, 0, 0);
            u = __builtin_amdgcn_mfma_f32_16x16x32_bf16(wB, hfB1, u, 0, 0, 0);
            float4 bv = *(const float4*)(c2b2 + nt * 16 + lg * 4);
            float v0 = u[0] + bv.x, v1 = u[1] + bv.y, v2 = u[2] + bv.z, v3 = u[3] + bv.w;
            S2 += v0 + v1 + v2 + v3;
            Q22 += v0 * v0 + v1 * v1 + v2 * v2 + v3 * v3;
        }
    }
    S1 += __shfl_xor(S1, 16); S1 += __shfl_xor(S1, 32);
    Q21 += __shfl_xor(Q21, 16); Q21 += __shfl_xor(Q21, 32);
    S2 += __shfl_xor(S2, 16); S2 += __shfl_xor(S2, 32);
    Q22 += __shfl_xor(Q22, 16); Q22 += __shfl_xor(Q22, 32);
    float mu1 = S1 * (1.f / 256.f), rs1 = rsqrtf(Q21 * (1.f / 256.f) - mu1 * mu1 + 1e-6f);
    float mu2 = S2 * (1.f / 256.f), rs2 = rsqrtf(Q22 * (1.f / 256.f) - mu2 * mu2 + 1e-6f);

    // ---------- GEMM2 pass B: recompute + LN + sigmoid + pooled -> LDS, NO unroll ----------
    #pragma clang loop unroll(disable)
    for (int nt = 0; nt < 16; ++nt) {
        float tm[4];
        {
            f32x4 u = {};
            bf16x8 wA = *(const bf16x8*)(wsb + 32768 + ((size_t)((nt * 2 + 0) * 64 + l)) * 8);
            bf16x8 wB = *(const bf16x8*)(wsb + 32768 + ((size_t)((nt * 2 + 1) * 64 + l)) * 8);
            u = __builtin_amdgcn_mfma_f32_16x16x32_bf16(wA, hfA0, u, 0, 0, 0);
            u = __builtin_amdgcn_mfma_f32_16x16x32_bf16(wB, hfA1, u, 0, 0, 0);
            float4 bv = *(const float4*)(c1b2 + nt * 16 + lg * 4);
            float4 gv = *(const float4*)(c1g  + nt * 16 + lg * 4);
            float4 ev = *(const float4*)(c1be + nt * 16 + lg * 4);
            float4 xv = *(const float4*)(srow + nt * 16 + lg * 4);
            float b4[4] = { bv.x, bv.y, bv.z, bv.w };
            float g4[4] = { gv.x, gv.y, gv.z, gv.w };
            float e4[4] = { ev.x, ev.y, ev.z, ev.w };
            float x4[4] = { xv.x, xv.y, xv.z, xv.w };
            #pragma unroll
            for (int r = 0; r < 4; ++r) {
                float ln = (u[r] + b4[r] - mu1) * rs1 * g4[r] + e4[r];
                float sg = 1.f / (1.f + __expf(-ln));
                tm[r] = 0.5f * sg * x4[r];
            }
        }
        {
            f32x4 u = {};
            bf16x8 wA = *(const bf16x8*)(wsb + 49152 + ((size_t)((nt * 2 + 0) * 64 + l)) * 8);
            bf16x8 wB = *(const bf16x8*)(wsb + 49152 + ((size_t)((nt * 2 + 1) * 64 + l)) * 8);
            u = __builtin_amdgcn_mfma_f32_16x16x32_bf16(wA, hfB0, u, 0, 0, 0);
            u = __builtin_amdgcn_mfma_f32_16x16x32_bf16(wB, hfB1, u, 0, 0, 0);
            float4 bv = *(const float4*)(c2b2 + nt * 16 + lg * 4);
            float4 gv = *(const float4*)(c2g  + nt * 16 + lg * 4);
            float4 ev = *(const float4*)(c2be + nt * 16 + lg * 4);
            float4 xv = *(const float4*)(erow + nt * 16 + lg * 4);
            float b4[4] = { bv.x, bv.y, bv.z, bv.w };
            float g4[4] = { gv.x, gv.y, gv.z, gv.w };
            float e4[4] = { ev.x, ev.y, ev.z, ev.w };
            float x4[4] = { xv.x, xv.y, xv.z, xv.w };
            float pm[4];
            #pragma unroll
            for (int r = 0; r < 4; ++r) {
                float ln = (u[r] + b4[r] - mu2) * rs2 * g4[r] + e4[r];
                float sg = 1.f / (1.f + __expf(-ln));
                pm[r] = tm[r] + 0.5f * sg * x4[r];
            }
            u32x2 wv;
            wv[0] = pk2(pm[0], pm[1]); wv[1] = pk2(pm[2], pm[3]);
            *(u32x2*)(pb + lr * 512 + ((nt * 32 + lg * 8) ^ swz)) = wv;
        }
    }
    asm volatile("s_waitcnt lgkmcnt(0)" ::: "memory");

    // ---------- gate GEMM, transposed loop, unroll 2: ga[16] in AGPRs ----------
    f32x4 ga[16] = {};
    const unsigned short* gwb = wsb + 65536;
    #pragma unroll 2
    for (int kk = 0; kk < 16; ++kk) {
        bf16x8 xk;
        if (kk < 8) {
            xk = *(const bf16x8*)(pb + lr * 512 + ((kk * 64 + lg * 16) ^ swz));
        } else {
            int k0 = (kk - 8) * 32 + lg * 8;
            float4 q0 = *(const float4*)(qrow + k0), q1 = *(const float4*)(qrow + k0 + 4);
            u32x4 a;
            a[0] = pk2(q0.x, q0.y); a[1] = pk2(q0.z, q0.w);
            a[2] = pk2(q1.x, q1.y); a[3] = pk2(q1.z, q1.w);
            xk = __builtin_bit_cast(bf16x8, a);
        }
        #pragma unroll
        for (int nt = 0; nt < 16; ++nt) {
            bf16x8 wf = *(const bf16x8*)(gwb + ((size_t)((nt * 16 + kk) * 64 + l)) * 8);
            ga[nt] = __builtin_amdgcn_mfma_f32_16x16x32_bf16(wf, xk, ga[nt], 0, 0, 0);
        }
    }

    // ---------- logits + softmax(2): MUST stay unrolled (ga[nt] const-indexed) ----------
    float t0 = 0.f, t1 = 0.f;
    #pragma unroll
    for (int nt = 0; nt < 16; ++nt) {
        float4 gbv = *(const float4*)(gb1 + nt * 16 + lg * 4);
        float4 w0v = *(const float4*)(gw2 + nt * 16 + lg * 4);
        float4 w1v = *(const float4*)(gw2 + 256 + nt * 16 + lg * 4);
        float gb4[4] = { gbv.x, gbv.y, gbv.z, gbv.w };
        float w04[4] = { w0v.x, w0v.y, w0v.z, w0v.w };
        float w14[4] = { w1v.x, w1v.y, w1v.z, w1v.w };
        #pragma unroll
        for (int r = 0; r < 4; ++r) {
            float hv = fmaxf(ga[nt][r] + gb4[r], 0.f);
            t0 += hv * w04[r]; t1 += hv * w14[r];
        }
    }
    t0 += __shfl_xor(t0, 16); t0 += __shfl_xor(t0, 32);
    t1 += __shfl_xor(t1, 16); t1 += __shfl_xor(t1, 32);
    float g0 = 1.f / (1.f + __expf((t1 + gb2[1]) - (t0 + gb2[0])));
    float g1 = 1.f - g0;

    // ---------- epilogue: pooled re-read from LDS, qf from global, NO unroll ----------
    float* orow = out + (size_t)(rowb + lr) * C;
    #pragma clang loop unroll(disable)
    for (int ks = 0; ks < 8; ++ks) {
        bf16x8 pf = *(const bf16x8*)(pb + lr * 512 + ((ks * 64 + lg * 16) ^ swz));
        u32x4 pu = __builtin_bit_cast(u32x4, pf);
        int k0 = ks * 32 + lg * 8;
        float4 q0 = *(const float4*)(qrow + k0), q1 = *(const float4*)(qrow + k0 + 4);
        float4 o0, o1;
        o0.x = bflo(pu[0]) * g0 + q0.x * g1;
        o0.y = bfhi(pu[0]) * g0 + q0.y * g1;
        o0.z = bflo(pu[1]) * g0 + q0.z * g1;
        o0.w = bfhi(pu[1]) * g0 + q0.w * g1;
        o1.x = bflo(pu[2]) * g0 + q1.x * g1;
        o1.y = bfhi(pu[2]) * g0 + q1.y * g1;
        o1.z = bflo(pu[3]) * g0 + q1.z * g1;
        o1.w = bfhi(pu[3]) * g0 + q1.w * g1;
        *(float4*)(orow + ks * 32 + lg * 8)     = o0;
        *(float4*)(orow + ks * 32 + lg * 8 + 4) = o1;
    }
}

extern "C" void kernel_launch(void* const* d_in, const int* in_sizes, int n_in,
                              void* d_out, int out_size, void* d_ws, size_t ws_size,
                              hipStream_t stream) {
    const float* feat  = (const float*)d_in[0];
    const float* qbox  = (const float*)d_in[1];
    const float* qfeat = (const float*)d_in[2];
    const float* posf  = (const float*)d_in[3];
    const float* c1w1  = (const float*)d_in[4];
    const float* c1b1  = (const float*)d_in[5];
    const float* c1w2  = (const float*)d_in[6];
    const float* c1b2  = (const float*)d_in[7];
    const float* c1g   = (const float*)d_in[8];
    const float* c1be  = (const float*)d_in[9];
    const float* c2w1  = (const float*)d_in[10];
    const float* c2b1  = (const float*)d_in[11];
    const float* c2w2  = (const float*)d_in[12];
    const float* c2b2  = (const float*)d_in[13];
    const float* c2g   = (const float*)d_in[14];
    const float* c2be  = (const float*)d_in[15];
    const float* gw1   = (const float*)d_in[16];
    const float* gb1   = (const float*)d_in[17];
    const float* gw2   = (const float*)d_in[18];
    const float* gb2   = (const float*)d_in[19];
    float* out = (float*)d_out;
    unsigned short* wsb = (unsigned short*)d_ws;   // 393216 B used

    prep_weights<<<96, 256, 0, stream>>>(c1w1, c2w1, c1w2, c2w2, gw1, wsb);

    dim3 grid((NB * NQ) / 64), block(256);         // 1024 blocks, 4 waves, 16 rows/wave
    semalign_v23<<<grid, block, 0, stream>>>(
        feat, qbox, qfeat, posf,
        c1b1, c1b2, c1g, c1be,
        c2b1, c2b2, c2g, c2be,
        gb1, gw2, gb2, wsb, out);
}

// Round 24
// 150.234 us; speedup vs baseline: 1.0345x; 1.0345x over previous
//
#include <hip/hip_runtime.h>
#include <hip/hip_bf16.h>
#include <math.h>

typedef __attribute__((ext_vector_type(8))) short bf16x8;
typedef __attribute__((ext_vector_type(4))) float f32x4;
typedef __attribute__((ext_vector_type(4))) unsigned int u32x4;
typedef __attribute__((ext_vector_type(2))) unsigned int u32x2;

constexpr int NB = 16, NQ = 4096, LF = 2048, C = 256;

__device__ __forceinline__ unsigned short bfbits(float x) {
    return __builtin_bit_cast(unsigned short, __float2bfloat16(x));
}
__device__ __forceinline__ unsigned pk2(float a, float b) {
    return (unsigned)bfbits(a) | ((unsigned)bfbits(b) << 16);
}
__device__ __forceinline__ float bflo(unsigned d) { return __builtin_bit_cast(float, d << 16); }
__device__ __forceinline__ float bfhi(unsigned d) { return __builtin_bit_cast(float, d & 0xffff0000u); }

// ---- prep: weights -> bf16 fragment-linear layout in ws (R4-verified) ----
__global__ void prep_weights(const float* __restrict__ c1w1, const float* __restrict__ c2w1,
                             const float* __restrict__ c1w2, const float* __restrict__ c2w2,
                             const float* __restrict__ gw1, unsigned short* __restrict__ ws)
{
    int t = blockIdx.x * 256 + threadIdx.x;          // 0..24575
    const float* src; int K, nks, dstoff, f;
    if (t < 2048)      { src = c1w1; K = 256; nks = 8;  dstoff = 0;      f = t; }
    else if (t < 4096) { src = c2w1; K = 256; nks = 8;  dstoff = 16384;  f = t - 2048; }
    else if (t < 6144) { src = c1w2; K = 64;  nks = 2;  dstoff = 32768;  f = t - 4096; }
    else if (t < 8192) { src = c2w2; K = 64;  nks = 2;  dstoff = 49152;  f = t - 6144; }
    else               { src = gw1;  K = 512; nks = 16; dstoff = 65536;  f = t - 8192; }
    int l = f & 63, s = f >> 6;
    int nt = s / nks, ks = s % nks;
    int n  = nt * 16 + (l & 15);
    int k0 = ks * 32 + (l >> 4) * 8;
    unsigned short* d = ws + dstoff + (size_t)f * 8;
    const float* sp = src + (size_t)n * K + k0;
    #pragma unroll
    for (int e = 0; e < 8; ++e) d[e] = bfbits(sp[e]);
}

// ---- main: v23 + s_setprio(1) around MFMA-dense regions (independent-wave regime) ----
__global__ __launch_bounds__(256, 4)
void semalign_v24(const float* __restrict__ feat,  const float* __restrict__ qbox,
                  const float* __restrict__ qfeat, const float* __restrict__ posf,
                  const float* __restrict__ c1b1,  const float* __restrict__ c1b2,
                  const float* __restrict__ c1g,   const float* __restrict__ c1be,
                  const float* __restrict__ c2b1,  const float* __restrict__ c2b2,
                  const float* __restrict__ c2g,   const float* __restrict__ c2be,
                  const float* __restrict__ gb1,   const float* __restrict__ gw2,
                  const float* __restrict__ gb2,
                  const unsigned short* __restrict__ wsb,
                  float* __restrict__ out)
{
    // per-wave 8 KiB region: H0 at +0 (2K), H1 at +2048 (2K) during GEMM1;
    // pooled [16][256] bf16 overwrites the whole region in pass B (H already in regs).
    __shared__ __align__(16) unsigned short sP[4][16][256];

    const int tid = threadIdx.x, l = tid & 63, wid = tid >> 6;
    const int lr = l & 15, lg = l >> 4;
    const int rowb = blockIdx.x * 64 + wid * 16;
    const int q = rowb >> 4;
    const int b = lr;
    const int swz = (lr & 7) << 4;

    const float* prow = posf  + ((size_t)b * NQ + q) * C;
    const float* qrow = qfeat + ((size_t)b * NQ + q) * C;
    float cx = qbox[((size_t)b * NQ + q) * 2 + 0];
    float w  = qbox[((size_t)b * NQ + q) * 2 + 1];
    float fs = fminf(fmaxf((cx - 0.5f * w) * (float)LF, 0.f), (float)(LF - 1));
    float fe = fminf(fmaxf((cx + 0.5f * w) * (float)LF, 0.f), (float)(LF - 1));
    const float* srow = feat + ((size_t)b * LF + (int)rintf(fs)) * C;
    const float* erow = feat + ((size_t)b * LF + (int)rintf(fe)) * C;

    // ---------- GEMM1: inline frags, unroll 2 ----------
    char* pb = (char*)&sP[wid][0][0];
    {
        f32x4 a1[4] = {}, a2[4] = {};
        #pragma unroll 2
        for (int ks = 0; ks < 8; ++ks) {
            int k0 = ks * 32 + lg * 8;
            float4 s0 = *(const float4*)(srow + k0), s1 = *(const float4*)(srow + k0 + 4);
            float4 e0 = *(const float4*)(erow + k0), e1 = *(const float4*)(erow + k0 + 4);
            float4 p0 = *(const float4*)(prow + k0), p1 = *(const float4*)(prow + k0 + 4);
            u32x4 av, cv;
            av[0] = pk2(s0.x * p0.x, s0.y * p0.y); av[1] = pk2(s0.z * p0.z, s0.w * p0.w);
            av[2] = pk2(s1.x * p1.x, s1.y * p1.y); av[3] = pk2(s1.z * p1.z, s1.w * p1.w);
            cv[0] = pk2(e0.x * p0.x, e0.y * p0.y); cv[1] = pk2(e0.z * p0.z, e0.w * p0.w);
            cv[2] = pk2(e1.x * p1.x, e1.y * p1.y); cv[3] = pk2(e1.z * p1.z, e1.w * p1.w);
            bf16x8 v1 = __builtin_bit_cast(bf16x8, av);
            bf16x8 v2 = __builtin_bit_cast(bf16x8, cv);
            __builtin_amdgcn_s_setprio(1);
            #pragma unroll
            for (int nt = 0; nt < 4; ++nt) {
                bf16x8 wA = *(const bf16x8*)(wsb + ((size_t)((nt * 8 + ks) * 64 + l)) * 8);
                bf16x8 wB = *(const bf16x8*)(wsb + 16384 + ((size_t)((nt * 8 + ks) * 64 + l)) * 8);
                a1[nt] = __builtin_amdgcn_mfma_f32_16x16x32_bf16(wA, v1, a1[nt], 0, 0, 0);
                a2[nt] = __builtin_amdgcn_mfma_f32_16x16x32_bf16(wB, v2, a2[nt], 0, 0, 0);
            }
            __builtin_amdgcn_s_setprio(0);
        }
        #pragma unroll
        for (int nt = 0; nt < 4; ++nt) {
            float4 b1v = *(const float4*)(c1b1 + nt * 16 + lg * 4);
            float4 b2v = *(const float4*)(c2b1 + nt * 16 + lg * 4);
            u32x2 wv;
            wv[0] = pk2(fmaxf(a1[nt][0] + b1v.x, 0.f), fmaxf(a1[nt][1] + b1v.y, 0.f));
            wv[1] = pk2(fmaxf(a1[nt][2] + b1v.z, 0.f), fmaxf(a1[nt][3] + b1v.w, 0.f));
            *(u32x2*)(pb + lr * 128 + ((nt * 32 + lg * 8) ^ swz)) = wv;
            wv[0] = pk2(fmaxf(a2[nt][0] + b2v.x, 0.f), fmaxf(a2[nt][1] + b2v.y, 0.f));
            wv[1] = pk2(fmaxf(a2[nt][2] + b2v.z, 0.f), fmaxf(a2[nt][3] + b2v.w, 0.f));
            *(u32x2*)(pb + 2048 + lr * 128 + ((nt * 32 + lg * 8) ^ swz)) = wv;
        }
    }

    // H frags for BOTH contrasts -> 16 VGPRs; LDS H region then dead
    asm volatile("s_waitcnt lgkmcnt(0)" ::: "memory");
    bf16x8 hfA0 = *(const bf16x8*)(pb + lr * 128 + ((0  + lg * 16) ^ swz));
    bf16x8 hfA1 = *(const bf16x8*)(pb + lr * 128 + ((64 + lg * 16) ^ swz));
    bf16x8 hfB0 = *(const bf16x8*)(pb + 2048 + lr * 128 + ((0  + lg * 16) ^ swz));
    bf16x8 hfB1 = *(const bf16x8*)(pb + 2048 + lr * 128 + ((64 + lg * 16) ^ swz));
    asm volatile("s_waitcnt lgkmcnt(0)" ::: "memory");

    // ---------- GEMM2 pass A: stats only, unroll 2, setprio around body ----------
    float S1 = 0.f, Q21 = 0.f, S2 = 0.f, Q22 = 0.f;
    #pragma unroll 2
    for (int nt = 0; nt < 16; ++nt) {
        __builtin_amdgcn_s_setprio(1);
        {
            f32x4 u = {};
            bf16x8 wA = *(const bf16x8*)(wsb + 32768 + ((size_t)((nt * 2 + 0) * 64 + l)) * 8);
            bf16x8 wB = *(const bf16x8*)(wsb + 32768 + ((size_t)((nt * 2 + 1) * 64 + l)) * 8);
            u = __builtin_amdgcn_mfma_f32_16x16x32_bf16(wA, hfA0, u, 0, 0, 0);
            u = __builtin_amdgcn_mfma_f32_16x16x32_bf16(wB, hfA1, u, 0, 0, 0);
            float4 bv = *(const float4*)(c1b2 + nt * 16 + lg * 4);
            float v0 = u[0] + bv.x, v1 = u[1] + bv.y, v2 = u[2] + bv.z, v3 = u[3] + bv.w;
            S1 += v0 + v1 + v2 + v3;
            Q21 += v0 * v0 + v1 * v1 + v2 * v2 + v3 * v3;
        }
        {
            f32x4 u = {};
            bf16x8 wA = *(const bf16x8*)(wsb + 49152 + ((size_t)((nt * 2 + 0) * 64 + l)) * 8);
            bf16x8 wB = *(const bf16x8*)(wsb + 49152 + ((size_t)((nt * 2 + 1) * 64 + l)) * 8);
            u = __builtin_amdgcn_mfma_f32_16x16x32_bf16(wA, hfB0, u, 0, 0, 0);
            u = __builtin_amdgcn_mfma_f32_16x16x32_bf16(wB, hfB1, u, 0, 0, 0);
            float4 bv = *(const float4*)(c2b2 + nt * 16 + lg * 4);
            float v0 = u[0] + bv.x, v1 = u[1] + bv.y, v2 = u[2] + bv.z, v3 = u[3] + bv.w;
            S2 += v0 + v1 + v2 + v3;
            Q22 += v0 * v0 + v1 * v1 + v2 * v2 + v3 * v3;
        }
        __builtin_amdgcn_s_setprio(0);
    }
    S1 += __shfl_xor(S1, 16); S1 += __shfl_xor(S1, 32);
    Q21 += __shfl_xor(Q21, 16); Q21 += __shfl_xor(Q21, 32);
    S2 += __shfl_xor(S2, 16); S2 += __shfl_xor(S2, 32);
    Q22 += __shfl_xor(Q22, 16); Q22 += __shfl_xor(Q22, 32);
    float mu1 = S1 * (1.f / 256.f), rs1 = rsqrtf(Q21 * (1.f / 256.f) - mu1 * mu1 + 1e-6f);
    float mu2 = S2 * (1.f / 256.f), rs2 = rsqrtf(Q22 * (1.f / 256.f) - mu2 * mu2 + 1e-6f);

    // ---------- GEMM2 pass B: recompute + LN + sigmoid + pooled -> LDS, NO unroll ----------
    #pragma clang loop unroll(disable)
    for (int nt = 0; nt < 16; ++nt) {
        float tm[4];
        {
            f32x4 u = {};
            bf16x8 wA = *(const bf16x8*)(wsb + 32768 + ((size_t)((nt * 2 + 0) * 64 + l)) * 8);
            bf16x8 wB = *(const bf16x8*)(wsb + 32768 + ((size_t)((nt * 2 + 1) * 64 + l)) * 8);
            u = __builtin_amdgcn_mfma_f32_16x16x32_bf16(wA, hfA0, u, 0, 0, 0);
            u = __builtin_amdgcn_mfma_f32_16x16x32_bf16(wB, hfA1, u, 0, 0, 0);
            float4 bv = *(const float4*)(c1b2 + nt * 16 + lg * 4);
            float4 gv = *(const float4*)(c1g  + nt * 16 + lg * 4);
            float4 ev = *(const float4*)(c1be + nt * 16 + lg * 4);
            float4 xv = *(const float4*)(srow + nt * 16 + lg * 4);
            float b4[4] = { bv.x, bv.y, bv.z, bv.w };
            float g4[4] = { gv.x, gv.y, gv.z, gv.w };
            float e4[4] = { ev.x, ev.y, ev.z, ev.w };
            float x4[4] = { xv.x, xv.y, xv.z, xv.w };
            #pragma unroll
            for (int r = 0; r < 4; ++r) {
                float ln = (u[r] + b4[r] - mu1) * rs1 * g4[r] + e4[r];
                float sg = 1.f / (1.f + __expf(-ln));
                tm[r] = 0.5f * sg * x4[r];
            }
        }
        {
            f32x4 u = {};
            bf16x8 wA = *(const bf16x8*)(wsb + 49152 + ((size_t)((nt * 2 + 0) * 64 + l)) * 8);
            bf16x8 wB = *(const bf16x8*)(wsb + 49152 + ((size_t)((nt * 2 + 1) * 64 + l)) * 8);
            u = __builtin_amdgcn_mfma_f32_16x16x32_bf16(wA, hfB0, u, 0, 0, 0);
            u = __builtin_amdgcn_mfma_f32_16x16x32_bf16(wB, hfB1, u, 0, 0, 0);
            float4 bv = *(const float4*)(c2b2 + nt * 16 + lg * 4);
            float4 gv = *(const float4*)(c2g  + nt * 16 + lg * 4);
            float4 ev = *(const float4*)(c2be + nt * 16 + lg * 4);
            float4 xv = *(const float4*)(erow + nt * 16 + lg * 4);
            float b4[4] = { bv.x, bv.y, bv.z, bv.w };
            float g4[4] = { gv.x, gv.y, gv.z, gv.w };
            float e4[4] = { ev.x, ev.y, ev.z, ev.w };
            float x4[4] = { xv.x, xv.y, xv.z, xv.w };
            float pm[4];
            #pragma unroll
            for (int r = 0; r < 4; ++r) {
                float ln = (u[r] + b4[r] - mu2) * rs2 * g4[r] + e4[r];
                float sg = 1.f / (1.f + __expf(-ln));
                pm[r] = tm[r] + 0.5f * sg * x4[r];
            }
            u32x2 wv;
            wv[0] = pk2(pm[0], pm[1]); wv[1] = pk2(pm[2], pm[3]);
            *(u32x2*)(pb + lr * 512 + ((nt * 32 + lg * 8) ^ swz)) = wv;
        }
    }
    asm volatile("s_waitcnt lgkmcnt(0)" ::: "memory");

    // ---------- gate GEMM, transposed loop, unroll 2: ga[16] in AGPRs, setprio on MFMAs ----------
    f32x4 ga[16] = {};
    const unsigned short* gwb = wsb + 65536;
    #pragma unroll 2
    for (int kk = 0; kk < 16; ++kk) {
        bf16x8 xk;
        if (kk < 8) {
            xk = *(const bf16x8*)(pb + lr * 512 + ((kk * 64 + lg * 16) ^ swz));
        } else {
            int k0 = (kk - 8) * 32 + lg * 8;
            float4 q0 = *(const float4*)(qrow + k0), q1 = *(const float4*)(qrow + k0 + 4);
            u32x4 a;
            a[0] = pk2(q0.x, q0.y); a[1] = pk2(q0.z, q0.w);
            a[2] = pk2(q1.x, q1.y); a[3] = pk2(q1.z, q1.w);
            xk = __builtin_bit_cast(bf16x8, a);
        }
        __builtin_amdgcn_s_setprio(1);
        #pragma unroll
        for (int nt = 0; nt < 16; ++nt) {
            bf16x8 wf = *(const bf16x8*)(gwb + ((size_t)((nt * 16 + kk) * 64 + l)) * 8);
            ga[nt] = __builtin_amdgcn_mfma_f32_16x16x32_bf16(wf, xk, ga[nt], 0, 0, 0);
        }
        __builtin_amdgcn_s_setprio(0);
    }

    // ---------- logits + softmax(2): MUST stay unrolled (ga[nt] const-indexed) ----------
    float t0 = 0.f, t1 = 0.f;
    #pragma unroll
    for (int nt = 0; nt < 16; ++nt) {
        float4 gbv = *(const float4*)(gb1 + nt * 16 + lg * 4);
        float4 w0v = *(const float4*)(gw2 + nt * 16 + lg * 4);
        float4 w1v = *(const float4*)(gw2 + 256 + nt * 16 + lg * 4);
        float gb4[4] = { gbv.x, gbv.y, gbv.z, gbv.w };
        float w04[4] = { w0v.x, w0v.y, w0v.z, w0v.w };
        float w14[4] = { w1v.x, w1v.y, w1v.z, w1v.w };
        #pragma unroll
        for (int r = 0; r < 4; ++r) {
            float hv = fmaxf(ga[nt][r] + gb4[r], 0.f);
            t0 += hv * w04[r]; t1 += hv * w14[r];
        }
    }
    t0 += __shfl_xor(t0, 16); t0 += __shfl_xor(t0, 32);
    t1 += __shfl_xor(t1, 16); t1 += __shfl_xor(t1, 32);
    float g0 = 1.f / (1.f + __expf((t1 + gb2[1]) - (t0 + gb2[0])));
    float g1 = 1.f - g0;

    // ---------- epilogue: pooled re-read from LDS, qf from global, NO unroll ----------
    float* orow = out + (size_t)(rowb + lr) * C;
    #pragma clang loop unroll(disable)
    for (int ks = 0; ks < 8; ++ks) {
        bf16x8 pf = *(const bf16x8*)(pb + lr * 512 + ((ks * 64 + lg * 16) ^ swz));
        u32x4 pu = __builtin_bit_cast(u32x4, pf);
        int k0 = ks * 32 + lg * 8;
        float4 q0 = *(const float4*)(qrow + k0), q1 = *(const float4*)(qrow + k0 + 4);
        float4 o0, o1;
        o0.x = bflo(pu[0]) * g0 + q0.x * g1;
        o0.y = bfhi(pu[0]) * g0 + q0.y * g1;
        o0.z = bflo(pu[1]) * g0 + q0.z * g1;
        o0.w = bfhi(pu[1]) * g0 + q0.w * g1;
        o1.x = bflo(pu[2]) * g0 + q1.x * g1;
        o1.y = bfhi(pu[2]) * g0 + q1.y * g1;
        o1.z = bflo(pu[3]) * g0 + q1.z * g1;
        o1.w = bfhi(pu[3]) * g0 + q1.w * g1;
        *(float4*)(orow + ks * 32 + lg * 8)     = o0;
        *(float4*)(orow + ks * 32 + lg * 8 + 4) = o1;
    }
}

extern "C" void kernel_launch(void* const* d_in, const int* in_sizes, int n_in,
                              void* d_out, int out_size, void* d_ws, size_t ws_size,
                              hipStream_t stream) {
    const float* feat  = (const float*)d_in[0];
    const float* qbox  = (const float*)d_in[1];
    const float* qfeat = (const float*)d_in[2];
    const float* posf  = (const float*)d_in[3];
    const float* c1w1  = (const float*)d_in[4];
    const float* c1b1  = (const float*)d_in[5];
    const float* c1w2  = (const float*)d_in[6];
    const float* c1b2  = (const float*)d_in[7];
    const float* c1g   = (const float*)d_in[8];
    const float* c1be  = (const float*)d_in[9];
    const float* c2w1  = (const float*)d_in[10];
    const float* c2b1  = (const float*)d_in[11];
    const float* c2w2  = (const float*)d_in[12];
    const float* c2b2  = (const float*)d_in[13];
    const float* c2g   = (const float*)d_in[14];
    const float* c2be  = (const float*)d_in[15];
    const float* gw1   = (const float*)d_in[16];
    const float* gb1   = (const float*)d_in[17];
    const float* gw2   = (const float*)d_in[18];
    const float* gb2   = (const float*)d_in[19];
    float* out = (float*)d_out;
    unsigned short* wsb = (unsigned short*)d_ws;   // 393216 B used

    prep_weights<<<96, 256, 0, stream>>>(c1w1, c2w1, c1w2, c2w2, gw1, wsb);

    dim3 grid((NB * NQ) / 64), block(256);         // 1024 blocks, 4 waves, 16 rows/wave
    semalign_v24<<<grid, block, 0, stream>>>(
        feat, qbox, qfeat, posf,
        c1b1, c1b2, c1g, c1be,
        c2b1, c2b2, c2g, c2be,
        gb1, gw2, gb2, wsb, out);
}